// Round 1
// baseline (4123.806 us; speedup 1.0000x reference)
//
#include <hip/hip_runtime.h>
#include <hip/hip_bf16.h>

#define N_NODES   100000
#define NODE_DIM  128
#define N_REL     32
#define N_EDGES_C 500000
#define H_DIM     192      // 3*MLP_DIM
#define P_COLS    384      // 2*H_DIM

// ---------------------------------------------------------------------------
// Kernel 0: Rb[r][j] = b1[j] + sum_k relation_emb[r][k] * W1[j][256+k]
// 32 blocks x 192 threads
// ---------------------------------------------------------------------------
__global__ void rel_precompute_kernel(const float* __restrict__ rel,
                                      const float* __restrict__ W1,
                                      const float* __restrict__ b1,
                                      float* __restrict__ Rb) {
    int r = blockIdx.x;
    int j = threadIdx.x;           // 0..191
    const float* re = rel + r * NODE_DIM;
    const float* w  = W1 + (size_t)j * P_COLS + 256;   // W1 row j, rel block
    float acc = b1[j];
    #pragma unroll 8
    for (int k = 0; k < NODE_DIM; ++k)
        acc = fmaf(re[k], w[k], acc);
    Rb[r * H_DIM + j] = acc;
}

// ---------------------------------------------------------------------------
// Kernel 1: P[n][c] = sum_k emb[n][k] * Beff[c][k]
//   Beff[c][k] = (c < 192) ? W1[c][k] : W1[c-192][128+k]
// 64x64 output tile per 256-thread block, BK=64, two K steps.
// Thread (ty,tx) computes rows {ty+16i}, cols {tx+16j}, i,j in 0..3.
// ---------------------------------------------------------------------------
__global__ __launch_bounds__(256) void node_precompute_kernel(
        const float* __restrict__ emb,
        const float* __restrict__ W1,
        float* __restrict__ P) {
    __shared__ float As[64][68];
    __shared__ float Bs[64][68];

    const int row0 = blockIdx.x * 64;
    const int col0 = blockIdx.y * 64;
    const int tid  = threadIdx.x;
    const int ty   = tid >> 4;
    const int tx   = tid & 15;

    // base pointer into W1 for this column tile (tiles never straddle halves)
    const float* w1base = W1 + ((col0 < H_DIM)
                                ? (size_t)col0 * P_COLS
                                : (size_t)(col0 - H_DIM) * P_COLS + NODE_DIM);

    float acc[4][4] = {};

    for (int ks = 0; ks < 2; ++ks) {
        // stage 64x64 f32 tiles: 1024 float4, 4 per thread
        #pragma unroll
        for (int t = 0; t < 4; ++t) {
            int idx = tid + t * 256;
            int r   = idx >> 4;           // 16 float4 per row
            int kc  = (idx & 15) << 2;
            float4 av = make_float4(0.f, 0.f, 0.f, 0.f);
            if (row0 + r < N_NODES)
                av = *(const float4*)(emb + (size_t)(row0 + r) * NODE_DIM + ks * 64 + kc);
            *(float4*)&As[r][kc] = av;
            float4 bv = *(const float4*)(w1base + (size_t)r * P_COLS + ks * 64 + kc);
            *(float4*)&Bs[r][kc] = bv;
        }
        __syncthreads();

        for (int k4 = 0; k4 < 16; ++k4) {
            float4 a[4], b[4];
            #pragma unroll
            for (int i = 0; i < 4; ++i)
                a[i] = *(const float4*)&As[ty + i * 16][k4 << 2];
            #pragma unroll
            for (int j = 0; j < 4; ++j)
                b[j] = *(const float4*)&Bs[tx + j * 16][k4 << 2];
            #pragma unroll
            for (int i = 0; i < 4; ++i)
                #pragma unroll
                for (int j = 0; j < 4; ++j) {
                    acc[i][j] = fmaf(a[i].x, b[j].x, acc[i][j]);
                    acc[i][j] = fmaf(a[i].y, b[j].y, acc[i][j]);
                    acc[i][j] = fmaf(a[i].z, b[j].z, acc[i][j]);
                    acc[i][j] = fmaf(a[i].w, b[j].w, acc[i][j]);
                }
        }
        __syncthreads();
    }

    #pragma unroll
    for (int i = 0; i < 4; ++i) {
        int r = row0 + ty + i * 16;
        if (r < N_NODES) {
            #pragma unroll
            for (int j = 0; j < 4; ++j)
                P[(size_t)r * P_COLS + col0 + tx + j * 16] = acc[i][j];
        }
    }
}

// ---------------------------------------------------------------------------
// Kernel 2: per edge, one wave (64 lanes, 3 elements each of 192):
//   h = relu(P[head,0:192] + P[tail,192:384] + Rb[type]); w = h.W2 + b2
//   out = sigmoid((logit(eps) + w) / T)
// ---------------------------------------------------------------------------
__global__ __launch_bounds__(256) void edge_kernel(
        const int* __restrict__ edge_index,
        const int* __restrict__ edge_type,
        const float* __restrict__ P,
        const float* __restrict__ Rb,
        const float* __restrict__ u,
        const float* __restrict__ W2,
        const float* __restrict__ b2,
        float* __restrict__ out) {
    int e = blockIdx.x * 4 + (threadIdx.x >> 6);
    if (e >= N_EDGES_C) return;
    int lane = threadIdx.x & 63;

    int head = edge_index[e];
    int tail = edge_index[N_EDGES_C + e];
    int rel  = edge_type[e];

    const float* Ph = P + (size_t)head * P_COLS;
    const float* Pt = P + (size_t)tail * P_COLS + H_DIM;
    const float* Rr = Rb + rel * H_DIM;

    float acc = 0.f;
    #pragma unroll
    for (int t = 0; t < 3; ++t) {
        int j = lane + t * 64;
        float h = Ph[j] + Pt[j] + Rr[j];
        h = fmaxf(h, 0.f);
        acc = fmaf(h, W2[j], acc);
    }
    #pragma unroll
    for (int off = 32; off; off >>= 1)
        acc += __shfl_xor(acc, off);

    if (lane == 0) {
        float weight = acc + b2[0];
        float uu  = u[e];
        float eps = fmaf(-0.9998f, uu, 0.9999f);            // (2B-1)*u + (1-B)
        float g   = (logf(eps) - log1pf(-eps) + weight) * 2.0f;  // / 0.5
        out[e] = 1.f / (1.f + expf(-g));
    }
}

// ---------------------------------------------------------------------------
extern "C" void kernel_launch(void* const* d_in, const int* in_sizes, int n_in,
                              void* d_out, int out_size, void* d_ws, size_t ws_size,
                              hipStream_t stream) {
    const int*   edge_index   = (const int*)d_in[0];
    const int*   edge_type    = (const int*)d_in[1];
    const float* all_embed    = (const float*)d_in[2];
    const float* relation_emb = (const float*)d_in[3];
    const float* u            = (const float*)d_in[4];
    const float* W1           = (const float*)d_in[5];
    const float* b1           = (const float*)d_in[6];
    const float* W2           = (const float*)d_in[7];
    const float* b2           = (const float*)d_in[8];
    float*       out          = (float*)d_out;

    float* P  = (float*)d_ws;                              // 100000 x 384
    float* Rb = P + (size_t)N_NODES * P_COLS;              // 32 x 192

    rel_precompute_kernel<<<N_REL, H_DIM, 0, stream>>>(relation_emb, W1, b1, Rb);

    dim3 grid1((N_NODES + 63) / 64, P_COLS / 64);
    node_precompute_kernel<<<grid1, 256, 0, stream>>>(all_embed, W1, P);

    edge_kernel<<<N_EDGES_C / 4, 256, 0, stream>>>(
        edge_index, edge_type, P, Rb, u, W2, b2, out);
}

// Round 2
// 238.612 us; speedup vs baseline: 17.2825x; 17.2825x over previous
//
#include <hip/hip_runtime.h>
#include <hip/hip_bf16.h>

#define N_NODES    100000
#define N_NODES_PAD 100096          // 782 * 128
#define NODE_DIM   128
#define N_REL      32
#define N_EDGES_C  500000
#define H_DIM      192              // 3*MLP_DIM
#define P_COLS     384              // 2*H_DIM

typedef __bf16 bf16x8 __attribute__((ext_vector_type(8)));
typedef float  f32x4  __attribute__((ext_vector_type(4)));

__device__ __forceinline__ ushort f2b(float x) {
    __hip_bfloat16 h = __float2bfloat16(x);     // RNE
    return *reinterpret_cast<ushort*>(&h);
}
__device__ __forceinline__ float b2f(ushort x) {
    union { unsigned u; float f; } v; v.u = ((unsigned)x) << 16; return v.f;
}

// ---------------------------------------------------------------------------
// Kernel A: all_embed f32 -> bf16, padded to N_NODES_PAD rows (pad = 0)
// ---------------------------------------------------------------------------
__global__ __launch_bounds__(256) void conv_emb_kernel(
        const float* __restrict__ in, ushort* __restrict__ out) {
    size_t i4 = ((size_t)blockIdx.x * 256 + threadIdx.x) * 4;
    const size_t n_real = (size_t)N_NODES * NODE_DIM;
    const size_t n_tot  = (size_t)N_NODES_PAD * NODE_DIM;
    if (i4 >= n_tot) return;
    if (i4 + 3 < n_real) {
        float4 v = *(const float4*)(in + i4);
        ushort4 o;
        o.x = f2b(v.x); o.y = f2b(v.y); o.z = f2b(v.z); o.w = f2b(v.w);
        *(ushort4*)(out + i4) = o;
    } else {
        #pragma unroll
        for (int t = 0; t < 4; ++t) {
            size_t i = i4 + t;
            if (i < n_tot) out[i] = (i < n_real) ? f2b(in[i]) : (ushort)0;
        }
    }
}

// ---------------------------------------------------------------------------
// Kernel B: Bmat[c][k] = bf16(Beff), c in [0,384), k in [0,128)
//   Beff[c][k] = (c < 192) ? W1[c][k] : W1[c-192][128+k]
// ---------------------------------------------------------------------------
__global__ __launch_bounds__(256) void build_b_kernel(
        const float* __restrict__ W1, ushort* __restrict__ Bmat) {
    int idx = blockIdx.x * 256 + threadIdx.x;      // 49152 total
    if (idx >= P_COLS * NODE_DIM) return;
    int c = idx >> 7, k = idx & 127;
    float v = (c < H_DIM) ? W1[(size_t)c * P_COLS + k]
                          : W1[(size_t)(c - H_DIM) * P_COLS + NODE_DIM + k];
    Bmat[idx] = f2b(v);
}

// ---------------------------------------------------------------------------
// Kernel C: Rb[r][j] = b1[j] + sum_k relation_emb[r][k] * W1[j][256+k]  (f32)
// ---------------------------------------------------------------------------
__global__ void rel_precompute_kernel(const float* __restrict__ rel,
                                      const float* __restrict__ W1,
                                      const float* __restrict__ b1,
                                      float* __restrict__ Rb) {
    int r = blockIdx.x;
    int j = threadIdx.x;           // 0..191
    const float* re = rel + r * NODE_DIM;
    const float* w  = W1 + (size_t)j * P_COLS + 2 * NODE_DIM;
    float acc = b1[j];
    #pragma unroll 8
    for (int k = 0; k < NODE_DIM; ++k)
        acc = fmaf(re[k], w[k], acc);
    Rb[r * H_DIM + j] = acc;
}

// ---------------------------------------------------------------------------
// Kernel D: MFMA GEMM  Pb[n][c] = bf16( sum_k embB[n][k] * Bmat[c][k] )
// Block: 256 thr = 4 waves; block tile 128 rows x 192 cols.
// Wave: 32 rows (2 row-frags) x 192 cols (12 col-frags), K = 128 (4 k-steps).
// mfma_f32_16x16x32_bf16:  A[r][k]: r=lane&15, k=(lane>>4)*8+j
//                          B[k][c]: c=lane&15, k=(lane>>4)*8+j
//                          D: col=lane&15, row=(lane>>4)*4+reg
// ---------------------------------------------------------------------------
__global__ __launch_bounds__(256) void node_mfma_kernel(
        const ushort* __restrict__ embB,
        const ushort* __restrict__ Bmat,
        ushort* __restrict__ Pb) {
    const int tid  = threadIdx.x;
    const int wid  = tid >> 6;
    const int lane = tid & 63;
    const int r16  = lane & 15;
    const int kgrp = lane >> 4;

    const int row_base = blockIdx.x * 128 + wid * 32;
    const int col0     = blockIdx.y * 192;

    const ushort* Abase = embB + (size_t)(row_base + r16) * NODE_DIM + kgrp * 8;
    const ushort* Bbase = Bmat + (size_t)(col0 + r16) * NODE_DIM + kgrp * 8;

    f32x4 acc[2][12] = {};

    #pragma unroll
    for (int ks = 0; ks < 4; ++ks) {
        bf16x8 a0 = *(const bf16x8*)(Abase + ks * 32);
        bf16x8 a1 = *(const bf16x8*)(Abase + 16 * NODE_DIM + ks * 32);
        #pragma unroll
        for (int ct = 0; ct < 12; ++ct) {
            bf16x8 b = *(const bf16x8*)(Bbase + (size_t)ct * 16 * NODE_DIM + ks * 32);
            acc[0][ct] = __builtin_amdgcn_mfma_f32_16x16x32_bf16(a0, b, acc[0][ct], 0, 0, 0);
            acc[1][ct] = __builtin_amdgcn_mfma_f32_16x16x32_bf16(a1, b, acc[1][ct], 0, 0, 0);
        }
    }

    #pragma unroll
    for (int rt = 0; rt < 2; ++rt) {
        int prow0 = row_base + rt * 16 + kgrp * 4;
        #pragma unroll
        for (int ct = 0; ct < 12; ++ct) {
            int pcol = col0 + ct * 16 + r16;
            #pragma unroll
            for (int reg = 0; reg < 4; ++reg) {
                int pr = prow0 + reg;
                if (pr < N_NODES)
                    Pb[(size_t)pr * P_COLS + pcol] = f2b(acc[rt][ct][reg]);
            }
        }
    }
}

// ---------------------------------------------------------------------------
// Kernel E: per edge (one wave): h = relu(Ph + Pt + Rb[type]); w = h.W2 + b2
//           out = sigmoid((logit(eps) + w) / T)
// ---------------------------------------------------------------------------
__global__ __launch_bounds__(256) void edge_kernel(
        const int* __restrict__ edge_index,
        const int* __restrict__ edge_type,
        const ushort* __restrict__ Pb,
        const float* __restrict__ Rb,
        const float* __restrict__ u,
        const float* __restrict__ W2,
        const float* __restrict__ b2,
        float* __restrict__ out) {
    int e = blockIdx.x * 4 + (threadIdx.x >> 6);
    if (e >= N_EDGES_C) return;
    int lane = threadIdx.x & 63;

    int head = edge_index[e];
    int tail = edge_index[N_EDGES_C + e];
    int rel  = edge_type[e];

    const ushort* Ph = Pb + (size_t)head * P_COLS;
    const ushort* Pt = Pb + (size_t)tail * P_COLS + H_DIM;
    const float*  Rr = Rb + rel * H_DIM;

    float acc = 0.f;
    #pragma unroll
    for (int t = 0; t < 3; ++t) {
        int j = lane + t * 64;
        float h = b2f(Ph[j]) + b2f(Pt[j]) + Rr[j];
        h = fmaxf(h, 0.f);
        acc = fmaf(h, W2[j], acc);
    }
    #pragma unroll
    for (int off = 32; off; off >>= 1)
        acc += __shfl_xor(acc, off);

    if (lane == 0) {
        float weight = acc + b2[0];
        float uu  = u[e];
        float eps = fmaf(-0.9998f, uu, 0.9999f);                 // (2B-1)*u + (1-B)
        float g   = (logf(eps) - log1pf(-eps) + weight) * 2.0f;  // / TEMPERATURE
        out[e] = 1.f / (1.f + expf(-g));
    }
}

// ---------------------------------------------------------------------------
extern "C" void kernel_launch(void* const* d_in, const int* in_sizes, int n_in,
                              void* d_out, int out_size, void* d_ws, size_t ws_size,
                              hipStream_t stream) {
    const int*   edge_index   = (const int*)d_in[0];
    const int*   edge_type    = (const int*)d_in[1];
    const float* all_embed    = (const float*)d_in[2];
    const float* relation_emb = (const float*)d_in[3];
    const float* u            = (const float*)d_in[4];
    const float* W1           = (const float*)d_in[5];
    const float* b1           = (const float*)d_in[6];
    const float* W2           = (const float*)d_in[7];
    const float* b2           = (const float*)d_in[8];
    float*       out          = (float*)d_out;

    char* ws = (char*)d_ws;
    ushort* embB = (ushort*)ws;                                   // 100096 x 128 bf16
    ws += (size_t)N_NODES_PAD * NODE_DIM * sizeof(ushort);
    ushort* Bmat = (ushort*)ws;                                   // 384 x 128 bf16
    ws += (size_t)P_COLS * NODE_DIM * sizeof(ushort);
    float*  Rb   = (float*)ws;                                    // 32 x 192 f32
    ws += (size_t)N_REL * H_DIM * sizeof(float);
    ushort* Pb   = (ushort*)ws;                                   // 100000 x 384 bf16

    {   // conv emb
        size_t n4 = ((size_t)N_NODES_PAD * NODE_DIM + 3) / 4;
        int blocks = (int)((n4 + 255) / 256);
        conv_emb_kernel<<<blocks, 256, 0, stream>>>(all_embed, embB);
    }
    build_b_kernel<<<(P_COLS * NODE_DIM + 255) / 256, 256, 0, stream>>>(W1, Bmat);
    rel_precompute_kernel<<<N_REL, H_DIM, 0, stream>>>(relation_emb, W1, b1, Rb);

    dim3 gridD(N_NODES_PAD / 128, P_COLS / 192);
    node_mfma_kernel<<<gridD, 256, 0, stream>>>(embB, Bmat, Pb);

    edge_kernel<<<N_EDGES_C / 4, 256, 0, stream>>>(
        edge_index, edge_type, Pb, Rb, u, W2, b2, out);
}

// Round 3
// 207.429 us; speedup vs baseline: 19.8806x; 1.1503x over previous
//
#include <hip/hip_runtime.h>
#include <hip/hip_bf16.h>

#define N_NODES     100000
#define N_NODES_PAD 100096          // 782 * 128
#define NODE_DIM    128
#define N_REL       32
#define N_EDGES_C   500000
#define H_DIM       192             // 3*MLP_DIM
#define P_COLS      384             // 2*H_DIM

typedef __bf16 bf16x8 __attribute__((ext_vector_type(8)));
typedef float  f32x4  __attribute__((ext_vector_type(4)));

__device__ __forceinline__ ushort f2b(float x) {
    __hip_bfloat16 h = __float2bfloat16(x);     // RNE
    return *reinterpret_cast<ushort*>(&h);
}

// unpack a packed pair of bf16 (one u32) into two floats: 1 VALU each
__device__ __forceinline__ void unpack2(unsigned v, float& lo, float& hi) {
    union { unsigned u; float f; } a, b;
    a.u = v << 16;
    b.u = v & 0xffff0000u;
    lo = a.f; hi = b.f;
}

// ---------------------------------------------------------------------------
// Kernel B: Bmat[c][k] = bf16(Beff), c in [0,384), k in [0,128)
//   Beff[c][k] = (c < 192) ? W1[c][k] : W1[c-192][128+k]
// ---------------------------------------------------------------------------
__global__ __launch_bounds__(256) void build_b_kernel(
        const float* __restrict__ W1, ushort* __restrict__ Bmat) {
    int idx = blockIdx.x * 256 + threadIdx.x;      // 49152 total
    if (idx >= P_COLS * NODE_DIM) return;
    int c = idx >> 7, k = idx & 127;
    float v = (c < H_DIM) ? W1[(size_t)c * P_COLS + k]
                          : W1[(size_t)(c - H_DIM) * P_COLS + NODE_DIM + k];
    Bmat[idx] = f2b(v);
}

// ---------------------------------------------------------------------------
// Kernel C: Rb[r][j] = b1[j] + sum_k relation_emb[r][k] * W1[j][256+k]  (f32)
// ---------------------------------------------------------------------------
__global__ void rel_precompute_kernel(const float* __restrict__ rel,
                                      const float* __restrict__ W1,
                                      const float* __restrict__ b1,
                                      float* __restrict__ Rb) {
    int r = blockIdx.x;
    int j = threadIdx.x;           // 0..191
    const float* re = rel + r * NODE_DIM;
    const float* w  = W1 + (size_t)j * P_COLS + 2 * NODE_DIM;
    float acc = b1[j];
    #pragma unroll 8
    for (int k = 0; k < NODE_DIM; ++k)
        acc = fmaf(re[k], w[k], acc);
    Rb[r * H_DIM + j] = acc;
}

// ---------------------------------------------------------------------------
// Kernel D: MFMA GEMM, fused f32->bf16 A conversion.
//   Pb[n][c] = bf16( sum_k all_embed[n][k] * Bmat[c][k] )
// Block: 256 thr = 4 waves; block tile 128 rows x 192 cols.
// Wave: 32 rows (2 row-frags) x 192 cols (12 col-frags), K = 128 (4 k-steps).
// mfma_f32_16x16x32_bf16:  A[r][k]: r=lane&15, k=(lane>>4)*8+j
//                          B[k][c]: c=lane&15, k=(lane>>4)*8+j
//                          D: col=lane&15, row=(lane>>4)*4+reg
// ---------------------------------------------------------------------------
__device__ __forceinline__ bf16x8 ld_a_frag(const float* p) {
    float4 v0 = *(const float4*)p;
    float4 v1 = *(const float4*)(p + 4);
    bf16x8 r;
    r[0] = (__bf16)v0.x; r[1] = (__bf16)v0.y; r[2] = (__bf16)v0.z; r[3] = (__bf16)v0.w;
    r[4] = (__bf16)v1.x; r[5] = (__bf16)v1.y; r[6] = (__bf16)v1.z; r[7] = (__bf16)v1.w;
    return r;
}

__global__ __launch_bounds__(256) void node_mfma_kernel(
        const float* __restrict__ embF,
        const ushort* __restrict__ Bmat,
        ushort* __restrict__ Pb) {
    const int tid  = threadIdx.x;
    const int wid  = tid >> 6;
    const int lane = tid & 63;
    const int r16  = lane & 15;
    const int kgrp = lane >> 4;

    const int row_base = blockIdx.x * 128 + wid * 32;
    const int col0     = blockIdx.y * 192;

    const int rowA0 = row_base + r16;
    const int rowA1 = rowA0 + 16;
    const float* A0 = embF + (size_t)rowA0 * NODE_DIM + kgrp * 8;
    const float* A1 = embF + (size_t)rowA1 * NODE_DIM + kgrp * 8;
    const ushort* Bbase = Bmat + (size_t)(col0 + r16) * NODE_DIM + kgrp * 8;

    const bf16x8 zf = {};
    f32x4 acc[2][12] = {};

    #pragma unroll
    for (int ks = 0; ks < 4; ++ks) {
        bf16x8 a0 = (rowA0 < N_NODES) ? ld_a_frag(A0 + ks * 32) : zf;
        bf16x8 a1 = (rowA1 < N_NODES) ? ld_a_frag(A1 + ks * 32) : zf;
        #pragma unroll
        for (int ct = 0; ct < 12; ++ct) {
            bf16x8 b = *(const bf16x8*)(Bbase + (size_t)ct * 16 * NODE_DIM + ks * 32);
            acc[0][ct] = __builtin_amdgcn_mfma_f32_16x16x32_bf16(a0, b, acc[0][ct], 0, 0, 0);
            acc[1][ct] = __builtin_amdgcn_mfma_f32_16x16x32_bf16(a1, b, acc[1][ct], 0, 0, 0);
        }
    }

    #pragma unroll
    for (int rt = 0; rt < 2; ++rt) {
        int prow0 = row_base + rt * 16 + kgrp * 4;
        #pragma unroll
        for (int ct = 0; ct < 12; ++ct) {
            int pcol = col0 + ct * 16 + r16;
            #pragma unroll
            for (int reg = 0; reg < 4; ++reg) {
                int pr = prow0 + reg;
                if (pr < N_NODES)
                    Pb[(size_t)pr * P_COLS + pcol] = f2b(acc[rt][ct][reg]);
            }
        }
    }
}

// ---------------------------------------------------------------------------
// Kernel E: ONE THREAD PER EDGE.
//   weight = W2 . relu(Ph[0:192] + Pt[192:384] + Rb[type]) + b2
//   out = sigmoid((logit(eps) + weight) / T)
// Each thread reads its two 384-B row halves as 24 independent uint4 loads
// (full cache-line consumption per thread, high MLP, no cross-lane reduce).
// ---------------------------------------------------------------------------
__global__ __launch_bounds__(256) void edge_kernel(
        const int* __restrict__ edge_index,
        const int* __restrict__ edge_type,
        const ushort* __restrict__ Pb,
        const float* __restrict__ Rb,
        const float* __restrict__ u,
        const float* __restrict__ W2,
        const float* __restrict__ b2,
        float* __restrict__ out) {
    int e = blockIdx.x * 256 + threadIdx.x;
    if (e >= N_EDGES_C) return;

    int head = edge_index[e];
    int tail = edge_index[N_EDGES_C + e];
    int rel  = edge_type[e];
    float uu = u[e];

    const ushort* Ph = Pb + (size_t)head * P_COLS;          // cols 0:192
    const ushort* Pt = Pb + (size_t)tail * P_COLS + H_DIM;  // cols 192:384
    const float*  Rr = Rb + rel * H_DIM;

    float acc0 = 0.f, acc1 = 0.f, acc2 = 0.f, acc3 = 0.f;

    #pragma unroll
    for (int c = 0; c < 24; ++c) {
        uint4  hv = *(const uint4*)(Ph + c * 8);
        uint4  tv = *(const uint4*)(Pt + c * 8);
        float4 r0 = *(const float4*)(Rr + c * 8);
        float4 r1 = *(const float4*)(Rr + c * 8 + 4);
        float4 w0 = *(const float4*)(W2 + c * 8);
        float4 w1 = *(const float4*)(W2 + c * 8 + 4);

        float h0,h1,h2,h3,h4,h5,h6,h7;
        float t0,t1,t2,t3,t4,t5,t6,t7;
        unpack2(hv.x, h0, h1); unpack2(hv.y, h2, h3);
        unpack2(hv.z, h4, h5); unpack2(hv.w, h6, h7);
        unpack2(tv.x, t0, t1); unpack2(tv.y, t2, t3);
        unpack2(tv.z, t4, t5); unpack2(tv.w, t6, t7);

        float s;
        s = fmaxf(h0 + t0 + r0.x, 0.f); acc0 = fmaf(s, w0.x, acc0);
        s = fmaxf(h1 + t1 + r0.y, 0.f); acc1 = fmaf(s, w0.y, acc1);
        s = fmaxf(h2 + t2 + r0.z, 0.f); acc2 = fmaf(s, w0.z, acc2);
        s = fmaxf(h3 + t3 + r0.w, 0.f); acc3 = fmaf(s, w0.w, acc3);
        s = fmaxf(h4 + t4 + r1.x, 0.f); acc0 = fmaf(s, w1.x, acc0);
        s = fmaxf(h5 + t5 + r1.y, 0.f); acc1 = fmaf(s, w1.y, acc1);
        s = fmaxf(h6 + t6 + r1.z, 0.f); acc2 = fmaf(s, w1.z, acc2);
        s = fmaxf(h7 + t7 + r1.w, 0.f); acc3 = fmaf(s, w1.w, acc3);
    }

    float weight = (acc0 + acc1) + (acc2 + acc3) + b2[0];
    float eps = fmaf(-0.9998f, uu, 0.9999f);                 // (2B-1)*u + (1-B)
    float g   = (logf(eps) - log1pf(-eps) + weight) * 2.0f;  // / TEMPERATURE
    out[e] = 1.f / (1.f + expf(-g));
}

// ---------------------------------------------------------------------------
extern "C" void kernel_launch(void* const* d_in, const int* in_sizes, int n_in,
                              void* d_out, int out_size, void* d_ws, size_t ws_size,
                              hipStream_t stream) {
    const int*   edge_index   = (const int*)d_in[0];
    const int*   edge_type    = (const int*)d_in[1];
    const float* all_embed    = (const float*)d_in[2];
    const float* relation_emb = (const float*)d_in[3];
    const float* u            = (const float*)d_in[4];
    const float* W1           = (const float*)d_in[5];
    const float* b1           = (const float*)d_in[6];
    const float* W2           = (const float*)d_in[7];
    const float* b2           = (const float*)d_in[8];
    float*       out          = (float*)d_out;

    char* ws = (char*)d_ws;
    ushort* Bmat = (ushort*)ws;                                   // 384 x 128 bf16
    ws += (size_t)P_COLS * NODE_DIM * sizeof(ushort);
    float*  Rb   = (float*)ws;                                    // 32 x 192 f32
    ws += (size_t)N_REL * H_DIM * sizeof(float);
    ushort* Pb   = (ushort*)ws;                                   // 100000 x 384 bf16

    build_b_kernel<<<(P_COLS * NODE_DIM + 255) / 256, 256, 0, stream>>>(W1, Bmat);
    rel_precompute_kernel<<<N_REL, H_DIM, 0, stream>>>(relation_emb, W1, b1, Rb);

    dim3 gridD(N_NODES_PAD / 128, P_COLS / 192);
    node_mfma_kernel<<<gridD, 256, 0, stream>>>(all_embed, Bmat, Pb);

    edge_kernel<<<(N_EDGES_C + 255) / 256, 256, 0, stream>>>(
        edge_index, edge_type, Pb, Rb, u, W2, b2, out);
}

// Round 4
// 138.722 us; speedup vs baseline: 29.7271x; 1.4953x over previous
//
#include <hip/hip_runtime.h>
#include <hip/hip_bf16.h>

#define N_NODES     100000
#define N_NODES_PAD 100096          // 782 * 128
#define NODE_DIM    128
#define N_REL       32
#define N_EDGES_C   500000
#define H_DIM       192             // 3*MLP_DIM
#define P_COLS      384             // 2*H_DIM

typedef __bf16 bf16x8 __attribute__((ext_vector_type(8)));
typedef float  f32x4  __attribute__((ext_vector_type(4)));

__device__ __forceinline__ ushort f2b(float x) {
    __hip_bfloat16 h = __float2bfloat16(x);     // RNE
    return *reinterpret_cast<ushort*>(&h);
}

// unpack a packed pair of bf16 (one u32) into two floats: 1 VALU each
__device__ __forceinline__ void unpack2(unsigned v, float& lo, float& hi) {
    union { unsigned u; float f; } a, b;
    a.u = v << 16;
    b.u = v & 0xffff0000u;
    lo = a.f; hi = b.f;
}

// ---------------------------------------------------------------------------
// Kernel B: Bmat[c][k] = bf16(Beff), c in [0,384), k in [0,128)
//   Beff[c][k] = (c < 192) ? W1[c][k] : W1[c-192][128+k]
// ---------------------------------------------------------------------------
__global__ __launch_bounds__(256) void build_b_kernel(
        const float* __restrict__ W1, ushort* __restrict__ Bmat) {
    int idx = blockIdx.x * 256 + threadIdx.x;      // 49152 total
    if (idx >= P_COLS * NODE_DIM) return;
    int c = idx >> 7, k = idx & 127;
    float v = (c < H_DIM) ? W1[(size_t)c * P_COLS + k]
                          : W1[(size_t)(c - H_DIM) * P_COLS + NODE_DIM + k];
    Bmat[idx] = f2b(v);
}

// ---------------------------------------------------------------------------
// Kernel C: Rb[r][j] = b1[j] + sum_k relation_emb[r][k] * W1[j][256+k]  (f32)
// ---------------------------------------------------------------------------
__global__ void rel_precompute_kernel(const float* __restrict__ rel,
                                      const float* __restrict__ W1,
                                      const float* __restrict__ b1,
                                      float* __restrict__ Rb) {
    int r = blockIdx.x;
    int j = threadIdx.x;           // 0..191
    const float* re = rel + r * NODE_DIM;
    const float* w  = W1 + (size_t)j * P_COLS + 2 * NODE_DIM;
    float acc = b1[j];
    #pragma unroll 8
    for (int k = 0; k < NODE_DIM; ++k)
        acc = fmaf(re[k], w[k], acc);
    Rb[r * H_DIM + j] = acc;
}

// ---------------------------------------------------------------------------
// Kernel D: MFMA GEMM, fused f32->bf16 A conversion.
//   Pb[n][c] = bf16( sum_k all_embed[n][k] * Bmat[c][k] )
// Block: 256 thr = 4 waves; block tile 128 rows x 192 cols.
// ---------------------------------------------------------------------------
__device__ __forceinline__ bf16x8 ld_a_frag(const float* p) {
    float4 v0 = *(const float4*)p;
    float4 v1 = *(const float4*)(p + 4);
    bf16x8 r;
    r[0] = (__bf16)v0.x; r[1] = (__bf16)v0.y; r[2] = (__bf16)v0.z; r[3] = (__bf16)v0.w;
    r[4] = (__bf16)v1.x; r[5] = (__bf16)v1.y; r[6] = (__bf16)v1.z; r[7] = (__bf16)v1.w;
    return r;
}

__global__ __launch_bounds__(256) void node_mfma_kernel(
        const float* __restrict__ embF,
        const ushort* __restrict__ Bmat,
        ushort* __restrict__ Pb) {
    const int tid  = threadIdx.x;
    const int wid  = tid >> 6;
    const int lane = tid & 63;
    const int r16  = lane & 15;
    const int kgrp = lane >> 4;

    const int row_base = blockIdx.x * 128 + wid * 32;
    const int col0     = blockIdx.y * 192;

    const int rowA0 = row_base + r16;
    const int rowA1 = rowA0 + 16;
    const float* A0 = embF + (size_t)rowA0 * NODE_DIM + kgrp * 8;
    const float* A1 = embF + (size_t)rowA1 * NODE_DIM + kgrp * 8;
    const ushort* Bbase = Bmat + (size_t)(col0 + r16) * NODE_DIM + kgrp * 8;

    const bf16x8 zf = {};
    f32x4 acc[2][12] = {};

    #pragma unroll
    for (int ks = 0; ks < 4; ++ks) {
        bf16x8 a0 = (rowA0 < N_NODES) ? ld_a_frag(A0 + ks * 32) : zf;
        bf16x8 a1 = (rowA1 < N_NODES) ? ld_a_frag(A1 + ks * 32) : zf;
        #pragma unroll
        for (int ct = 0; ct < 12; ++ct) {
            bf16x8 b = *(const bf16x8*)(Bbase + (size_t)ct * 16 * NODE_DIM + ks * 32);
            acc[0][ct] = __builtin_amdgcn_mfma_f32_16x16x32_bf16(a0, b, acc[0][ct], 0, 0, 0);
            acc[1][ct] = __builtin_amdgcn_mfma_f32_16x16x32_bf16(a1, b, acc[1][ct], 0, 0, 0);
        }
    }

    #pragma unroll
    for (int rt = 0; rt < 2; ++rt) {
        int prow0 = row_base + rt * 16 + kgrp * 4;
        #pragma unroll
        for (int ct = 0; ct < 12; ++ct) {
            int pcol = col0 + ct * 16 + r16;
            #pragma unroll
            for (int reg = 0; reg < 4; ++reg) {
                int pr = prow0 + reg;
                if (pr < N_NODES)
                    Pb[(size_t)pr * P_COLS + pcol] = f2b(acc[rt][ct][reg]);
            }
        }
    }
}

// ---------------------------------------------------------------------------
// Kernel E: 8 LANES PER EDGE (8 edges per wave, 32 per block).
// Each lane loads one uint4 (16B) per 128B line; an 8-lane group consumes
// exactly one cache line per load instruction. 6 P-loads in flight per lane.
//   weight = W2 . relu(Ph[0:192] + Pt[192:384] + Rb[type]) + b2
//   out = sigmoid((logit(eps) + weight) / T)
// ---------------------------------------------------------------------------
__global__ __launch_bounds__(256) void edge_kernel(
        const int* __restrict__ edge_index,
        const int* __restrict__ edge_type,
        const ushort* __restrict__ Pb,
        const float* __restrict__ Rb,
        const float* __restrict__ u,
        const float* __restrict__ W2,
        const float* __restrict__ b2,
        float* __restrict__ out) {
    const int tid  = threadIdx.x;
    const int wave = tid >> 6;
    const int lane = tid & 63;
    const int g    = lane >> 3;       // edge slot within wave, 0..7
    const int sub  = lane & 7;        // element-chunk slot, 0..7

    const int e = blockIdx.x * 32 + wave * 8 + g;   // 15625*32 == 500000 exact

    const int head = edge_index[e];
    const int tail = edge_index[N_EDGES_C + e];
    const int rel  = edge_type[e];

    const ushort* Ph = Pb + (size_t)head * P_COLS;          // cols 0:192
    const ushort* Pt = Pb + (size_t)tail * P_COLS + H_DIM;  // cols 192:384
    const int j0 = sub * 8;                                  // this lane's base elem

    // issue all 6 random-row loads up front (independent, one line per group)
    uint4 h0 = *(const uint4*)(Ph + j0);
    uint4 h1 = *(const uint4*)(Ph + j0 + 64);
    uint4 h2 = *(const uint4*)(Ph + j0 + 128);
    uint4 t0 = *(const uint4*)(Pt + j0);
    uint4 t1 = *(const uint4*)(Pt + j0 + 64);
    uint4 t2 = *(const uint4*)(Pt + j0 + 128);

    const float* Rr = Rb + rel * H_DIM + j0;   // L1-resident (24KB table)
    const float* Wp = W2 + j0;                 // L1-resident (768B)

    float acc = 0.f;
    #pragma unroll
    for (int c = 0; c < 3; ++c) {
        uint4 hv = (c == 0) ? h0 : (c == 1) ? h1 : h2;
        uint4 tv = (c == 0) ? t0 : (c == 1) ? t1 : t2;
        float4 r0 = *(const float4*)(Rr + c * 64);
        float4 r1 = *(const float4*)(Rr + c * 64 + 4);
        float4 w0 = *(const float4*)(Wp + c * 64);
        float4 w1 = *(const float4*)(Wp + c * 64 + 4);

        float h0f,h1f,h2f,h3f,h4f,h5f,h6f,h7f;
        float t0f,t1f,t2f,t3f,t4f,t5f,t6f,t7f;
        unpack2(hv.x, h0f, h1f); unpack2(hv.y, h2f, h3f);
        unpack2(hv.z, h4f, h5f); unpack2(hv.w, h6f, h7f);
        unpack2(tv.x, t0f, t1f); unpack2(tv.y, t2f, t3f);
        unpack2(tv.z, t4f, t5f); unpack2(tv.w, t6f, t7f);

        float s;
        s = fmaxf(h0f + t0f + r0.x, 0.f); acc = fmaf(s, w0.x, acc);
        s = fmaxf(h1f + t1f + r0.y, 0.f); acc = fmaf(s, w0.y, acc);
        s = fmaxf(h2f + t2f + r0.z, 0.f); acc = fmaf(s, w0.z, acc);
        s = fmaxf(h3f + t3f + r0.w, 0.f); acc = fmaf(s, w0.w, acc);
        s = fmaxf(h4f + t4f + r1.x, 0.f); acc = fmaf(s, w1.x, acc);
        s = fmaxf(h5f + t5f + r1.y, 0.f); acc = fmaf(s, w1.y, acc);
        s = fmaxf(h6f + t6f + r1.z, 0.f); acc = fmaf(s, w1.z, acc);
        s = fmaxf(h7f + t7f + r1.w, 0.f); acc = fmaf(s, w1.w, acc);
    }

    // reduce across the 8-lane group
    acc += __shfl_xor(acc, 1);
    acc += __shfl_xor(acc, 2);
    acc += __shfl_xor(acc, 4);

    if (sub == 0) {
        float weight = acc + b2[0];
        float uu  = u[e];
        float eps = fmaf(-0.9998f, uu, 0.9999f);                 // (2B-1)*u + (1-B)
        float gi  = (logf(eps) - log1pf(-eps) + weight) * 2.0f;  // / TEMPERATURE
        out[e] = 1.f / (1.f + expf(-gi));
    }
}

// ---------------------------------------------------------------------------
extern "C" void kernel_launch(void* const* d_in, const int* in_sizes, int n_in,
                              void* d_out, int out_size, void* d_ws, size_t ws_size,
                              hipStream_t stream) {
    const int*   edge_index   = (const int*)d_in[0];
    const int*   edge_type    = (const int*)d_in[1];
    const float* all_embed    = (const float*)d_in[2];
    const float* relation_emb = (const float*)d_in[3];
    const float* u            = (const float*)d_in[4];
    const float* W1           = (const float*)d_in[5];
    const float* b1           = (const float*)d_in[6];
    const float* W2           = (const float*)d_in[7];
    const float* b2           = (const float*)d_in[8];
    float*       out          = (float*)d_out;

    char* ws = (char*)d_ws;
    ushort* Bmat = (ushort*)ws;                                   // 384 x 128 bf16
    ws += (size_t)P_COLS * NODE_DIM * sizeof(ushort);
    float*  Rb   = (float*)ws;                                    // 32 x 192 f32
    ws += (size_t)N_REL * H_DIM * sizeof(float);
    ushort* Pb   = (ushort*)ws;                                   // 100000 x 384 bf16

    build_b_kernel<<<(P_COLS * NODE_DIM + 255) / 256, 256, 0, stream>>>(W1, Bmat);
    rel_precompute_kernel<<<N_REL, H_DIM, 0, stream>>>(relation_emb, W1, b1, Rb);

    dim3 gridD(N_NODES_PAD / 128, P_COLS / 192);
    node_mfma_kernel<<<gridD, 256, 0, stream>>>(all_embed, Bmat, Pb);

    edge_kernel<<<N_EDGES_C / 32, 256, 0, stream>>>(
        edge_index, edge_type, Pb, Rb, u, W2, b2, out);
}

// Round 5
// 135.553 us; speedup vs baseline: 30.4221x; 1.0234x over previous
//
#include <hip/hip_runtime.h>
#include <hip/hip_bf16.h>

#define N_NODES     100000
#define N_NODES_PAD 100096          // 782 * 128
#define NODE_DIM    128
#define N_REL       32
#define N_EDGES_C   500000
#define H_DIM       192             // 3*MLP_DIM
#define P_COLS      384             // 2*H_DIM

typedef __bf16 bf16x8 __attribute__((ext_vector_type(8)));
typedef float  f32x4  __attribute__((ext_vector_type(4)));

__device__ __forceinline__ ushort f2b(float x) {
    __hip_bfloat16 h = __float2bfloat16(x);     // RNE
    return *reinterpret_cast<ushort*>(&h);
}

// unpack a packed pair of bf16 (one u32) into two floats: 1 VALU each
__device__ __forceinline__ void unpack2(unsigned v, float& lo, float& hi) {
    union { unsigned u; float f; } a, b;
    a.u = v << 16;
    b.u = v & 0xffff0000u;
    lo = a.f; hi = b.f;
}

// ---------------------------------------------------------------------------
// Kernel B: Bmat[c][k] = bf16(Beff), c in [0,384), k in [0,128)
//   Beff[c][k] = (c < 192) ? W1[c][k] : W1[c-192][128+k]
// ---------------------------------------------------------------------------
__global__ __launch_bounds__(256) void build_b_kernel(
        const float* __restrict__ W1, ushort* __restrict__ Bmat) {
    int idx = blockIdx.x * 256 + threadIdx.x;      // 49152 total
    if (idx >= P_COLS * NODE_DIM) return;
    int c = idx >> 7, k = idx & 127;
    float v = (c < H_DIM) ? W1[(size_t)c * P_COLS + k]
                          : W1[(size_t)(c - H_DIM) * P_COLS + NODE_DIM + k];
    Bmat[idx] = f2b(v);
}

// ---------------------------------------------------------------------------
// Kernel C: Rb[r][j] = b1[j] + sum_k relation_emb[r][k] * W1[j][256+k]  (f32)
// ---------------------------------------------------------------------------
__global__ void rel_precompute_kernel(const float* __restrict__ rel,
                                      const float* __restrict__ W1,
                                      const float* __restrict__ b1,
                                      float* __restrict__ Rb) {
    int r = blockIdx.x;
    int j = threadIdx.x;           // 0..191
    const float* re = rel + r * NODE_DIM;
    const float* w  = W1 + (size_t)j * P_COLS + 2 * NODE_DIM;
    float acc = b1[j];
    #pragma unroll 8
    for (int k = 0; k < NODE_DIM; ++k)
        acc = fmaf(re[k], w[k], acc);
    Rb[r * H_DIM + j] = acc;
}

// ---------------------------------------------------------------------------
// Kernel D: MFMA GEMM, fused f32->bf16 A conversion, 16-deep A prefetch.
//   Pb[n][c] = bf16( sum_k all_embed[n][k] * Bmat[c][k] )
// Block: 256 thr = 4 waves; block tile 128 rows x 192 cols.
// Wave: 32 rows (2 row-frags) x 192 cols (12 col-frags), K = 128 (4 k-steps).
// Row indices are CLAMPED (not predicated) so all loads are unconditional
// and hoistable; pad rows compute garbage, writes remain guarded.
// ---------------------------------------------------------------------------
__global__ __launch_bounds__(256) void node_mfma_kernel(
        const float* __restrict__ embF,
        const ushort* __restrict__ Bmat,
        ushort* __restrict__ Pb) {
    const int tid  = threadIdx.x;
    const int wid  = tid >> 6;
    const int lane = tid & 63;
    const int r16  = lane & 15;
    const int kgrp = lane >> 4;

    const int row_base = blockIdx.x * 128 + wid * 32;
    const int col0     = blockIdx.y * 192;

    const int rowA0 = min(row_base + r16,      N_NODES - 1);
    const int rowA1 = min(row_base + r16 + 16, N_NODES - 1);
    const float* A0 = embF + (size_t)rowA0 * NODE_DIM + kgrp * 8;
    const float* A1 = embF + (size_t)rowA1 * NODE_DIM + kgrp * 8;
    const ushort* Bbase = Bmat + (size_t)(col0 + r16) * NODE_DIM + kgrp * 8;

    // ---- prefetch ALL A data: 16 independent 16B HBM loads in flight ----
    float4 af[2][4][2];
    #pragma unroll
    for (int ks = 0; ks < 4; ++ks) {
        af[0][ks][0] = *(const float4*)(A0 + ks * 32);
        af[0][ks][1] = *(const float4*)(A0 + ks * 32 + 4);
        af[1][ks][0] = *(const float4*)(A1 + ks * 32);
        af[1][ks][1] = *(const float4*)(A1 + ks * 32 + 4);
    }

    // ---- convert to bf16 fragments ----
    bf16x8 a[2][4];
    #pragma unroll
    for (int rt = 0; rt < 2; ++rt)
        #pragma unroll
        for (int ks = 0; ks < 4; ++ks) {
            float4 v0 = af[rt][ks][0];
            float4 v1 = af[rt][ks][1];
            bf16x8 r;
            r[0] = (__bf16)v0.x; r[1] = (__bf16)v0.y;
            r[2] = (__bf16)v0.z; r[3] = (__bf16)v0.w;
            r[4] = (__bf16)v1.x; r[5] = (__bf16)v1.y;
            r[6] = (__bf16)v1.z; r[7] = (__bf16)v1.w;
            a[rt][ks] = r;
        }

    // ---- MFMA main loop; B is L2/L3-resident (96 KB table) ----
    f32x4 acc[2][12] = {};
    #pragma unroll
    for (int ks = 0; ks < 4; ++ks) {
        #pragma unroll
        for (int ct = 0; ct < 12; ++ct) {
            bf16x8 b = *(const bf16x8*)(Bbase + (size_t)ct * 16 * NODE_DIM + ks * 32);
            acc[0][ct] = __builtin_amdgcn_mfma_f32_16x16x32_bf16(a[0][ks], b, acc[0][ct], 0, 0, 0);
            acc[1][ct] = __builtin_amdgcn_mfma_f32_16x16x32_bf16(a[1][ks], b, acc[1][ct], 0, 0, 0);
        }
    }

    // ---- epilogue: D layout col=lane&15, row=(lane>>4)*4+reg ----
    #pragma unroll
    for (int rt = 0; rt < 2; ++rt) {
        int prow0 = row_base + rt * 16 + kgrp * 4;
        #pragma unroll
        for (int ct = 0; ct < 12; ++ct) {
            int pcol = col0 + ct * 16 + r16;
            #pragma unroll
            for (int reg = 0; reg < 4; ++reg) {
                int pr = prow0 + reg;
                if (pr < N_NODES)
                    Pb[(size_t)pr * P_COLS + pcol] = f2b(acc[rt][ct][reg]);
            }
        }
    }
}

// ---------------------------------------------------------------------------
// Kernel E: 8 LANES PER EDGE (8 edges per wave, 32 per block).
// Each lane loads one uint4 (16B); an 8-lane group consumes exactly one
// 128B cache line per load instruction. 6 P-loads in flight per lane.
//   weight = W2 . relu(Ph[0:192] + Pt[192:384] + Rb[type]) + b2
//   out = sigmoid((logit(eps) + weight) / T)
// ---------------------------------------------------------------------------
__global__ __launch_bounds__(256) void edge_kernel(
        const int* __restrict__ edge_index,
        const int* __restrict__ edge_type,
        const ushort* __restrict__ Pb,
        const float* __restrict__ Rb,
        const float* __restrict__ u,
        const float* __restrict__ W2,
        const float* __restrict__ b2,
        float* __restrict__ out) {
    const int tid  = threadIdx.x;
    const int wave = tid >> 6;
    const int lane = tid & 63;
    const int g    = lane >> 3;       // edge slot within wave, 0..7
    const int sub  = lane & 7;        // element-chunk slot, 0..7

    const int e = blockIdx.x * 32 + wave * 8 + g;   // 15625*32 == 500000 exact

    const int head = edge_index[e];
    const int tail = edge_index[N_EDGES_C + e];
    const int rel  = edge_type[e];

    const ushort* Ph = Pb + (size_t)head * P_COLS;          // cols 0:192
    const ushort* Pt = Pb + (size_t)tail * P_COLS + H_DIM;  // cols 192:384
    const int j0 = sub * 8;                                  // this lane's base elem

    // issue all 6 random-row loads up front (independent, one line per group)
    uint4 h0 = *(const uint4*)(Ph + j0);
    uint4 h1 = *(const uint4*)(Ph + j0 + 64);
    uint4 h2 = *(const uint4*)(Ph + j0 + 128);
    uint4 t0 = *(const uint4*)(Pt + j0);
    uint4 t1 = *(const uint4*)(Pt + j0 + 64);
    uint4 t2 = *(const uint4*)(Pt + j0 + 128);

    const float* Rr = Rb + rel * H_DIM + j0;   // L1-resident (24KB table)
    const float* Wp = W2 + j0;                 // L1-resident (768B)

    float acc = 0.f;
    #pragma unroll
    for (int c = 0; c < 3; ++c) {
        uint4 hv = (c == 0) ? h0 : (c == 1) ? h1 : h2;
        uint4 tv = (c == 0) ? t0 : (c == 1) ? t1 : t2;
        float4 r0 = *(const float4*)(Rr + c * 64);
        float4 r1 = *(const float4*)(Rr + c * 64 + 4);
        float4 w0 = *(const float4*)(Wp + c * 64);
        float4 w1 = *(const float4*)(Wp + c * 64 + 4);

        float h0f,h1f,h2f,h3f,h4f,h5f,h6f,h7f;
        float t0f,t1f,t2f,t3f,t4f,t5f,t6f,t7f;
        unpack2(hv.x, h0f, h1f); unpack2(hv.y, h2f, h3f);
        unpack2(hv.z, h4f, h5f); unpack2(hv.w, h6f, h7f);
        unpack2(tv.x, t0f, t1f); unpack2(tv.y, t2f, t3f);
        unpack2(tv.z, t4f, t5f); unpack2(tv.w, t6f, t7f);

        float s;
        s = fmaxf(h0f + t0f + r0.x, 0.f); acc = fmaf(s, w0.x, acc);
        s = fmaxf(h1f + t1f + r0.y, 0.f); acc = fmaf(s, w0.y, acc);
        s = fmaxf(h2f + t2f + r0.z, 0.f); acc = fmaf(s, w0.z, acc);
        s = fmaxf(h3f + t3f + r0.w, 0.f); acc = fmaf(s, w0.w, acc);
        s = fmaxf(h4f + t4f + r1.x, 0.f); acc = fmaf(s, w1.x, acc);
        s = fmaxf(h5f + t5f + r1.y, 0.f); acc = fmaf(s, w1.y, acc);
        s = fmaxf(h6f + t6f + r1.z, 0.f); acc = fmaf(s, w1.z, acc);
        s = fmaxf(h7f + t7f + r1.w, 0.f); acc = fmaf(s, w1.w, acc);
    }

    // reduce across the 8-lane group
    acc += __shfl_xor(acc, 1);
    acc += __shfl_xor(acc, 2);
    acc += __shfl_xor(acc, 4);

    if (sub == 0) {
        float weight = acc + b2[0];
        float uu  = u[e];
        float eps = fmaf(-0.9998f, uu, 0.9999f);                 // (2B-1)*u + (1-B)
        float gi  = (logf(eps) - log1pf(-eps) + weight) * 2.0f;  // / TEMPERATURE
        out[e] = 1.f / (1.f + expf(-gi));
    }
}

// ---------------------------------------------------------------------------
extern "C" void kernel_launch(void* const* d_in, const int* in_sizes, int n_in,
                              void* d_out, int out_size, void* d_ws, size_t ws_size,
                              hipStream_t stream) {
    const int*   edge_index   = (const int*)d_in[0];
    const int*   edge_type    = (const int*)d_in[1];
    const float* all_embed    = (const float*)d_in[2];
    const float* relation_emb = (const float*)d_in[3];
    const float* u            = (const float*)d_in[4];
    const float* W1           = (const float*)d_in[5];
    const float* b1           = (const float*)d_in[6];
    const float* W2           = (const float*)d_in[7];
    const float* b2           = (const float*)d_in[8];
    float*       out          = (float*)d_out;

    char* ws = (char*)d_ws;
    ushort* Bmat = (ushort*)ws;                                   // 384 x 128 bf16
    ws += (size_t)P_COLS * NODE_DIM * sizeof(ushort);
    float*  Rb   = (float*)ws;                                    // 32 x 192 f32
    ws += (size_t)N_REL * H_DIM * sizeof(float);
    ushort* Pb   = (ushort*)ws;                                   // 100000 x 384 bf16

    build_b_kernel<<<(P_COLS * NODE_DIM + 255) / 256, 256, 0, stream>>>(W1, Bmat);
    rel_precompute_kernel<<<N_REL, H_DIM, 0, stream>>>(relation_emb, W1, b1, Rb);

    dim3 gridD(N_NODES_PAD / 128, P_COLS / 192);
    node_mfma_kernel<<<gridD, 256, 0, stream>>>(all_embed, Bmat, Pb);

    edge_kernel<<<N_EDGES_C / 32, 256, 0, stream>>>(
        edge_index, edge_type, Pb, Rb, u, W2, b2, out);
}